// Round 10
// baseline (166.981 us; speedup 1.0000x reference)
//
#include <hip/hip_runtime.h>

typedef __attribute__((ext_vector_type(8))) __bf16 bf16x8;
typedef __attribute__((ext_vector_type(8))) unsigned short ushort8;
typedef __attribute__((ext_vector_type(4))) float f32x4;

constexpr int C_ = 32, NN = 64;
constexpr int PK = 3375;              // 15^3
constexpr int K_TOT = 108000;         // C*PK
constexpr int F_TOT = 1024;
constexpr int M_TOT = 128;            // B*N
constexpr int KSTEPS = 3375;          // K_TOT/32

__device__ __forceinline__ unsigned short f2bf(float f) {
    unsigned int b = __builtin_bit_cast(unsigned int, f);
    b += 0x7FFFu + ((b >> 16) & 1u);      // round-to-nearest-even
    return (unsigned short)(b >> 16);
}

// async 16B global -> LDS. LDS dest: wave-uniform base, HW writes lane i at
// base + i*16. Global source address is PER-LANE (m173) -> gather swizzle free.
__device__ __forceinline__ void async_copy16(void* lds, const void* g) {
    __builtin_amdgcn_global_load_lds(
        (const __attribute__((address_space(1))) unsigned int*)g,
        (__attribute__((address_space(3))) unsigned int*)lds, 16, 0, 0);
}

// ---------------- kernel 1: patch gather -> bf16 A natural [m][K] layout ---------
__global__ void extract_kernel(const float* __restrict__ x,
                               const int* __restrict__ cent,
                               unsigned short* __restrict__ Af) {
    int m = blockIdx.x;            // 0..127  (b*64+n)
    int c = blockIdx.y;            // 0..31
    int b = m >> 6, n = m & 63;
    int cx = cent[(b * NN + n) * 3 + 0];
    int cy = cent[(b * NN + n) * 3 + 1];
    int cz = cent[(b * NN + n) * 3 + 2];
    int sx = max(cx - 7, 0), ex = min(cx + 8, 96);
    int sy = max(cy - 7, 0), ey = min(cy + 8, 96);
    int sz = max(cz - 7, 0), ez = min(cz + 8, 96);
    const float* xb = x + (size_t)(b * C_ + c) * (96 * 96 * 96);
    unsigned short* Arow = Af + (size_t)m * K_TOT + (size_t)c * PK;
    for (int k = threadIdx.x; k < PK; k += blockDim.x) {
        int iz = k % 15;
        int t  = k / 15;
        int iy = t % 15;
        int ix = t / 15;
        int hx = sx + ix, wy = sy + iy, dz = sz + iz;
        float v = 0.0f;
        if (hx < ex && wy < ey && dz < ez)
            v = xb[(hx * 96 + wy) * 96 + dz];
        Arow[k] = f2bf(v);
    }
}

// ---------------- kernel 2: split-K GEMM, BARRIER-FREE per-wave pipeline ---------
// Tile: M=128 x F=256 per block, k-step 32, 4 waves. Each wave owns a PRIVATE
// LDS slice: its 64-f W quarter (8KB) + its own copy of the A step-tile (8KB),
// both double-buffered (128KB/block). No wave reads another wave's LDS ->
// the K-loop has ZERO barriers; each wave free-runs, paced only by its own
// counted vmcnt(16). Wave/block sawteeth de-phase -> flat HBM demand.
// A duplication is L2-served (same bytes re-read within ~us). Grid (64,4):
// dispatch id = by*64+bx -> id%8 = s%8, so the 4 fx-mates of chunk s share an
// XCD and together consume full 4KB W rows.
__global__ __launch_bounds__(256, 1) void gemm_kernel(const unsigned short* __restrict__ Af,
                                                      const float* __restrict__ W,
                                                      float* __restrict__ partial,
                                                      int CS) {
    __shared__ __align__(16) unsigned char smem[4 * 32768];   // 128 KB
    int s  = blockIdx.x;                       // K-chunk (0..63)
    int fx = blockIdx.y;                       // 0..3 : 256-col F tile
    int st0 = s * CS;
    int st1 = min(st0 + CS, KSTEPS);
    int f0  = fx * 256;

    int tid  = (int)threadIdx.x;
    int wave = tid >> 6, lane = tid & 63;
    int fr = lane & 15, lgrp = lane >> 4;
    int f0w = f0 + wave * 64;                  // this wave's 64-col W slice

    unsigned char* region = smem + wave * 32768;   // private: W0,A0,W1,A1 (8KB each)

    f32x4 acc[8][4];
#pragma unroll
    for (int i = 0; i < 8; ++i)
#pragma unroll
        for (int j = 0; j < 4; ++j) acc[i][j] = (f32x4)(0.0f);

    // per wave per step: 8 W ops (quarter tile 32k x 64f fp32, rows 256B, op =
    // 4 rows) + 8 A ops (fragment-gather, op = one mt kilobyte). 16 vmcnt events.
    auto STAGE = [&](int buf, int st) {
        int k0 = st << 5;
        unsigned char* wb = region + buf * 16384;
        const float* wsrc = W + ((size_t)k0 + (lane >> 4)) * F_TOT + f0w + ((lane & 15) << 2);
#pragma unroll
        for (int r = 0; r < 8; ++r)
            async_copy16(wb + r * 1024, wsrc + (size_t)(r * 4) * F_TOT);
        unsigned char* ab = wb + 8192;
        const unsigned short* ag = Af + (size_t)fr * K_TOT + k0 + lgrp * 8;
#pragma unroll
        for (int mt = 0; mt < 8; ++mt)
            async_copy16(ab + mt * 1024, ag + (size_t)(mt * 16) * K_TOT);
    };

    auto COMPUTE = [&](int buf) {
        const unsigned char* wb = region + buf * 16384;
        const unsigned char* ab = wb + 8192;
        bf16x8 afrag[8];
#pragma unroll
        for (int mt = 0; mt < 8; ++mt)      // ds_read_b128, lane-consecutive 16B
            afrag[mt] = *reinterpret_cast<const bf16x8*>(ab + mt * 1024 + lane * 16);
#pragma unroll
        for (int ft = 0; ft < 4; ++ft) {
            int fl4 = (ft * 16 + fr) << 2;
            float wv[8];
#pragma unroll
            for (int j = 0; j < 8; ++j)
                wv[j] = *reinterpret_cast<const float*>(wb + (lgrp * 8 + j) * 256 + fl4);
            ushort8 bt;
#pragma unroll
            for (int j = 0; j < 8; ++j) bt[j] = f2bf(wv[j]);
            bf16x8 bfrag = __builtin_bit_cast(bf16x8, bt);
#pragma unroll
            for (int mt = 0; mt < 8; ++mt)
                acc[mt][ft] = __builtin_amdgcn_mfma_f32_16x16x32_bf16(afrag[mt], bfrag, acc[mt][ft], 0, 0, 0);
        }
    };

    int cur = 0;
    STAGE(0, st0);
    for (int t = st0; t < st1 - 1; ++t) {
        STAGE(cur ^ 1, t + 1);
        // own stage(t) fully landed; stage(t+1)'s 16 ops stay in flight. No barrier.
        asm volatile("s_waitcnt vmcnt(16)" ::: "memory");
        COMPUTE(cur);
        cur ^= 1;
    }
    asm volatile("s_waitcnt vmcnt(0)" ::: "memory");
    COMPUTE(cur);

    // --- write partials: D row = lgrp*4 + r, col = fr (m89-verified mapping) ---
    float* pout = partial + (size_t)s * (M_TOT * F_TOT);
#pragma unroll
    for (int mt = 0; mt < 8; ++mt) {
        int mbase = mt * 16 + lgrp * 4;
#pragma unroll
        for (int ft = 0; ft < 4; ++ft) {
            int f = f0w + ft * 16 + fr;
#pragma unroll
            for (int r = 0; r < 4; ++r)
                pout[(size_t)(mbase + r) * F_TOT + f] = acc[mt][ft][r];
        }
    }
}

// ---------------- kernel 3: split-K reduce + bias (vectorized) ----------------
__global__ void reduce_kernel(const float* __restrict__ partial,
                              const float* __restrict__ bias,
                              float* __restrict__ out, int S) {
    int i4 = (blockIdx.x * blockDim.x + threadIdx.x) * 4;
    if (i4 >= M_TOT * F_TOT) return;
    f32x4 a = *reinterpret_cast<const f32x4*>(bias + (i4 & (F_TOT - 1)));
    for (int s = 0; s < S; ++s)
        a += *reinterpret_cast<const f32x4*>(partial + (size_t)s * (M_TOT * F_TOT) + i4);
    *reinterpret_cast<f32x4*>(out + i4) = a;
}

extern "C" void kernel_launch(void* const* d_in, const int* in_sizes, int n_in,
                              void* d_out, int out_size, void* d_ws, size_t ws_size,
                              hipStream_t stream) {
    const float* x    = (const float*)d_in[0];
    const int*   cent = (const int*)d_in[1];
    const float* W    = (const float*)d_in[2];
    const float* bias = (const float*)d_in[3];
    float* out = (float*)d_out;

    unsigned short* Af = (unsigned short*)d_ws;
    size_t Af_bytes = (size_t)M_TOT * K_TOT * 2;                 // 27,648,000
    float* partial = (float*)((char*)d_ws + Af_bytes);

    size_t avail = ws_size > Af_bytes ? ws_size - Af_bytes : 0;
    int S = (int)(avail / ((size_t)M_TOT * F_TOT * 4));
    if (S > 64) S = 64;                   // grid (64,4) = 256 blocks = 1/CU
    if (S < 1)  S = 1;
    int CS = (KSTEPS + S - 1) / S;        // 53 for S=64
    S = (KSTEPS + CS - 1) / CS;           // 64 (last chunk = 36 steps)

    extract_kernel<<<dim3(M_TOT, C_), 256, 0, stream>>>(x, cent, Af);
    gemm_kernel<<<dim3(S, 4), 256, 0, stream>>>(Af, W, partial, CS);
    reduce_kernel<<<dim3((M_TOT * F_TOT + 1023) / 1024, 1, 1), 256, 0, stream>>>(partial, bias, out, S);
}

// Round 11
// 141.040 us; speedup vs baseline: 1.1839x; 1.1839x over previous
//
#include <hip/hip_runtime.h>

typedef __attribute__((ext_vector_type(8))) __bf16 bf16x8;
typedef __attribute__((ext_vector_type(8))) unsigned short ushort8;
typedef __attribute__((ext_vector_type(4))) float f32x4;

constexpr int C_ = 32, NN = 64;
constexpr int PK = 3375;              // 15^3
constexpr int K_TOT = 108000;         // C*PK
constexpr int F_TOT = 1024;
constexpr int M_TOT = 128;            // B*N
constexpr int KSTEPS = 3375;          // K_TOT/32

// GEMM LDS geometry (F-tile 256): W tile 32k x 256f fp32 stored as 16 row-PAIRS
// of (2048 data + 16 pad) bytes -> B-column reads 2-way aliased (free, m136),
// async dests stay 16B-aligned. Triple-buffered: 3 x (WBUF + ABUF) = 123,648 B.
constexpr int WPAIR  = 2064;
constexpr int WBUF   = 16 * WPAIR;    // 33,024
constexpr int ABUF   = 8192;          // 32k x 128m bf16, fragment-ordered in LDS
constexpr int RBUF   = WBUF + ABUF;   // 41,216 (16B-aligned)

__device__ __forceinline__ unsigned short f2bf(float f) {
    unsigned int b = __builtin_bit_cast(unsigned int, f);
    b += 0x7FFFu + ((b >> 16) & 1u);      // round-to-nearest-even
    return (unsigned short)(b >> 16);
}

// async 16B global -> LDS. LDS dest: wave-uniform base, HW writes lane i at
// base + i*16. Global source address is PER-LANE (m173) -> gather swizzle free.
__device__ __forceinline__ void async_copy16(void* lds, const void* g) {
    __builtin_amdgcn_global_load_lds(
        (const __attribute__((address_space(1))) unsigned int*)g,
        (__attribute__((address_space(3))) unsigned int*)lds, 16, 0, 0);
}

// ---------------- kernel 1: patch gather -> bf16 A natural [m][K] layout ---------
__global__ void extract_kernel(const float* __restrict__ x,
                               const int* __restrict__ cent,
                               unsigned short* __restrict__ Af) {
    int m = blockIdx.x;            // 0..127  (b*64+n)
    int c = blockIdx.y;            // 0..31
    int b = m >> 6, n = m & 63;
    int cx = cent[(b * NN + n) * 3 + 0];
    int cy = cent[(b * NN + n) * 3 + 1];
    int cz = cent[(b * NN + n) * 3 + 2];
    int sx = max(cx - 7, 0), ex = min(cx + 8, 96);
    int sy = max(cy - 7, 0), ey = min(cy + 8, 96);
    int sz = max(cz - 7, 0), ez = min(cz + 8, 96);
    const float* xb = x + (size_t)(b * C_ + c) * (96 * 96 * 96);
    unsigned short* Arow = Af + (size_t)m * K_TOT + (size_t)c * PK;
    for (int k = threadIdx.x; k < PK; k += blockDim.x) {
        int iz = k % 15;
        int t  = k / 15;
        int iy = t % 15;
        int ix = t / 15;
        int hx = sx + ix, wy = sy + iy, dz = sz + iz;
        float v = 0.0f;
        if (hx < ex && wy < ey && dz < ez)
            v = xb[(hx * 96 + wy) * 96 + dz];
        Arow[k] = f2bf(v);
    }
}

// ---------------- kernel 2: split-K GEMM, F-tile 256, TRIPLE-buffer + vmcnt(20) --
// R9 structure (best: 143.6us) with lookahead-2: per wave per step 10 contiguous
// global_load_lds ops (8 W 1KB-rows + 2 A frag-gathers); steady wait vmcnt(20)
// keeps TWO steps' loads in flight across each barrier (sawtooth halved, op
// contiguity unchanged -- the R10 lesson). Grid (64,4): id%8 = s%8 -> the 4
// fx-mates of chunk s share an XCD, together consuming full 4KB W rows.
__global__ __launch_bounds__(256, 1) void gemm_kernel(const unsigned short* __restrict__ Af,
                                                      const float* __restrict__ W,
                                                      unsigned short* __restrict__ partial,
                                                      int CS) {
    __shared__ __align__(16) unsigned char smem[3 * RBUF];     // 123,648 B
    int s  = blockIdx.x;                       // K-chunk (0..63)
    int fx = blockIdx.y;                       // 0..3 : 256-col F tile
    int st0 = s * CS;
    int st1 = min(st0 + CS, KSTEPS);
    int f0  = fx * 256;

    int tid  = (int)threadIdx.x;
    int wave = tid >> 6, lane = tid & 63;
    int fr = lane & 15, lgrp = lane >> 4;

    f32x4 acc[8][4];
#pragma unroll
    for (int i = 0; i < 8; ++i)
#pragma unroll
        for (int j = 0; j < 4; ++j) acc[i][j] = (f32x4)(0.0f);

    // per wave per step: 8 W half-pairs (contiguous 1KB rows) + 2 A frag-gathers
    auto STAGE = [&](int buf, int st) {
        int k0 = st << 5;
        unsigned char* wb = smem + buf * RBUF;
        const float* wsrc = W + (size_t)k0 * F_TOT + f0 + (lane << 2);
#pragma unroll
        for (int r = 0; r < 8; ++r) {
            int row = r * 4 + wave;            // 0..31
            async_copy16(wb + (row >> 1) * WPAIR + (row & 1) * 1024,
                         wsrc + (size_t)row * F_TOT);
        }
        unsigned char* ab = wb + WBUF;
        const unsigned short* ag = Af + (size_t)fr * K_TOT + k0 + lgrp * 8;
#pragma unroll
        for (int i = 0; i < 2; ++i) {
            int mt = wave * 2 + i;
            async_copy16(ab + mt * 1024, ag + (size_t)(mt * 16) * K_TOT);
        }
    };

    auto COMPUTE = [&](int buf) {
        const unsigned char* wb = smem + buf * RBUF;
        const unsigned char* ab = wb + WBUF;
        bf16x8 afrag[8];
#pragma unroll
        for (int mt = 0; mt < 8; ++mt)      // ds_read_b128, lane-consecutive 16B
            afrag[mt] = *reinterpret_cast<const bf16x8*>(ab + mt * 1024 + lane * 16);
#pragma unroll
        for (int ft = 0; ft < 4; ++ft) {
            int fl4 = (wave * 64 + ft * 16 + fr) * 4;
            float wv[8];
#pragma unroll
            for (int j = 0; j < 8; ++j) {
                int row = lgrp * 8 + j;
                wv[j] = *reinterpret_cast<const float*>(
                            wb + (row >> 1) * WPAIR + (row & 1) * 1024 + fl4);
            }
            ushort8 bt;
#pragma unroll
            for (int j = 0; j < 8; ++j) bt[j] = f2bf(wv[j]);
            bf16x8 bfrag = __builtin_bit_cast(bf16x8, bt);
#pragma unroll
            for (int mt = 0; mt < 8; ++mt)
                acc[mt][ft] = __builtin_amdgcn_mfma_f32_16x16x32_bf16(afrag[mt], bfrag, acc[mt][ft], 0, 0, 0);
        }
    };

    int len = st1 - st0;
    STAGE(0, st0);
    if (len > 1) STAGE(1, st0 + 1);
    int t = st0, cb = 0;
    for (; t + 2 < st1; ++t) {
        int sb = cb + 2; if (sb >= 3) sb -= 3;
        STAGE(sb, t + 2);
        asm volatile("s_waitcnt vmcnt(20)" ::: "memory");  // stage(t) done; t+1,t+2 in flight
        __builtin_amdgcn_s_barrier();
        COMPUTE(cb);
        __builtin_amdgcn_s_barrier();
        if (++cb == 3) cb = 0;
    }
    if (t + 1 < st1) {                                      // two steps left
        asm volatile("s_waitcnt vmcnt(10)" ::: "memory");
        __builtin_amdgcn_s_barrier();
        COMPUTE(cb);
        __builtin_amdgcn_s_barrier();
        if (++cb == 3) cb = 0;
        ++t;
    }
    asm volatile("s_waitcnt vmcnt(0)" ::: "memory");
    __builtin_amdgcn_s_barrier();
    COMPUTE(cb);

    // --- write bf16 partials: D row = lgrp*4 + r, col = fr (m89 mapping) ---
    unsigned short* pout = partial + (size_t)s * (M_TOT * F_TOT);
#pragma unroll
    for (int mt = 0; mt < 8; ++mt) {
        int mbase = mt * 16 + lgrp * 4;
#pragma unroll
        for (int ft = 0; ft < 4; ++ft) {
            int f = f0 + wave * 64 + ft * 16 + fr;
#pragma unroll
            for (int r = 0; r < 4; ++r)
                pout[(size_t)(mbase + r) * F_TOT + f] = f2bf(acc[mt][ft][r]);
        }
    }
}

// ---------------- kernel 3: split-K reduce (bf16 partials) + bias ----------------
__global__ void reduce_kernel(const unsigned short* __restrict__ partial,
                              const float* __restrict__ bias,
                              float* __restrict__ out, int S) {
    int i8 = (blockIdx.x * blockDim.x + threadIdx.x) * 8;
    if (i8 >= M_TOT * F_TOT) return;
    float a[8];
#pragma unroll
    for (int j = 0; j < 8; ++j) a[j] = bias[(i8 & (F_TOT - 1)) + j];
    for (int s = 0; s < S; ++s) {
        ushort8 p = *reinterpret_cast<const ushort8*>(partial + (size_t)s * (M_TOT * F_TOT) + i8);
#pragma unroll
        for (int j = 0; j < 8; ++j)
            a[j] += __builtin_bit_cast(float, (unsigned int)p[j] << 16);
    }
#pragma unroll
    for (int j = 0; j < 8; ++j) out[i8 + j] = a[j];
}

extern "C" void kernel_launch(void* const* d_in, const int* in_sizes, int n_in,
                              void* d_out, int out_size, void* d_ws, size_t ws_size,
                              hipStream_t stream) {
    const float* x    = (const float*)d_in[0];
    const int*   cent = (const int*)d_in[1];
    const float* W    = (const float*)d_in[2];
    const float* bias = (const float*)d_in[3];
    float* out = (float*)d_out;

    unsigned short* Af = (unsigned short*)d_ws;
    size_t Af_bytes = (size_t)M_TOT * K_TOT * 2;                 // 27,648,000
    unsigned short* partial = (unsigned short*)((char*)d_ws + Af_bytes);

    size_t avail = ws_size > Af_bytes ? ws_size - Af_bytes : 0;
    int S = (int)(avail / ((size_t)M_TOT * F_TOT * 2));
    if (S > 64) S = 64;                   // grid (64,4) = 256 blocks = 1/CU
    if (S < 1)  S = 1;
    int CS = (KSTEPS + S - 1) / S;        // 53 for S=64
    S = (KSTEPS + CS - 1) / CS;           // 64 (last chunk = 36 steps)

    extract_kernel<<<dim3(M_TOT, C_), 256, 0, stream>>>(x, cent, Af);
    gemm_kernel<<<dim3(S, 4), 256, 0, stream>>>(Af, W, partial, CS);
    reduce_kernel<<<dim3((M_TOT * F_TOT) / (256 * 8)), 256, 0, stream>>>(partial, bias, out, S);
}